// Round 6
// baseline (94.848 us; speedup 1.0000x reference)
//
#include <hip/hip_runtime.h>
#include <cstddef>

// Hyperbolic supervised contrastive loss, fused, MFMA split-bf16 Gram.
// G = F F^T with F = hi + lo (bf16 split): G ~= hi*hi^T + hi*lo^T + lo*hi^T.
// logits_max cancels (softmax shift invariance).
// Row-stationary, one 128x128 tile per block (grid 32x32 = 1024 blocks = 4/CU:
// round 5 was latency-bound at 2 blocks/CU / 19% occupancy).
// Row stats -> per-split partial stores (no atomics), parallel finalize.
// exp(logit) = ratio^20, logit = 20*ln2*log2(ratio), ratio=(|den|-r)/(|den|+r).

typedef __bf16 bf16x8 __attribute__((ext_vector_type(8)));
typedef __bf16 bf16x4 __attribute__((ext_vector_type(4)));
typedef float  f32x4  __attribute__((ext_vector_type(4)));

#define C_CONST 0.01f
#define RATIO_MIN 5.000025e-06f           // ratio at clamp 1-1e-5
#define LOGIT_SCALE 13.86294361119890619f // 20*ln(2)
#define TEMP 0.5f
#define LN2 0.69314718055994530942f
constexpr int DD = 128;
constexpr int NSPLIT = 32;   // one 128-col tile per split
constexpr int FBLK = 16;     // finalize blocks

// bf16-split + row squared-norms. 8 rows/block, 32 lanes/row.
__global__ __launch_bounds__(256) void prep_kernel(
    const float* __restrict__ F, __bf16* __restrict__ Fh, __bf16* __restrict__ Fl,
    float* __restrict__ sq) {
  const int tid = threadIdx.x;
  const int lane = tid & 31;
  const int row = blockIdx.x * 8 + (tid >> 5);
  const float4 v = *reinterpret_cast<const float4*>(F + (size_t)row * DD + lane * 4);
  float s = v.x * v.x + v.y * v.y + v.z * v.z + v.w * v.w;
  bf16x4 h, lo;
  h[0] = (__bf16)v.x; lo[0] = (__bf16)(v.x - (float)h[0]);
  h[1] = (__bf16)v.y; lo[1] = (__bf16)(v.y - (float)h[1]);
  h[2] = (__bf16)v.z; lo[2] = (__bf16)(v.z - (float)h[2]);
  h[3] = (__bf16)v.w; lo[3] = (__bf16)(v.w - (float)h[3]);
  *reinterpret_cast<bf16x4*>(Fh + (size_t)row * DD + lane * 4) = h;
  *reinterpret_cast<bf16x4*>(Fl + (size_t)row * DD + lane * 4) = lo;
#pragma unroll
  for (int off = 1; off < 32; off <<= 1) s += __shfl_xor(s, off);
  if (lane == 0) sq[row] = s;
}

// 4 waves; wave w owns rows row0..row0+31 (2 row-frags x 8 col-frags).
// A frags hoisted to regs, B frags streamed from L2 per fj.
// C/D layout (verified m89): value r of frag (fi,fj) at
// row = row0 + fi*16 + lg*4 + r, col = col0 + fj*16 + ln.
__global__ __launch_bounds__(256, 4) void gram_kernel(
    const __bf16* __restrict__ Fh, const __bf16* __restrict__ Fl,
    const float* __restrict__ sq, const int* __restrict__ labels,
    float* __restrict__ dpart, float* __restrict__ ppart, float* __restrict__ npart,
    int B) {
  const int tid = threadIdx.x;
  const int l  = tid & 63;
  const int w  = tid >> 6;
  const int lg = l >> 4, ln = l & 15;
  const int row0 = blockIdx.x * 128 + w * 32;
  const int s = blockIdx.y;
  const int col0 = s * 128;

  const __bf16* Ah = Fh + (size_t)(row0 + ln) * DD + lg * 8;
  const __bf16* Al = Fl + (size_t)(row0 + ln) * DD + lg * 8;
  const __bf16* Bh = Fh + (size_t)(col0 + ln) * DD + lg * 8;
  const __bf16* Bl = Fl + (size_t)(col0 + ln) * DD + lg * 8;

  // hoist all A fragments (16 x 16B = 64 VGPR)
  bf16x8 ah[2][4], al[2][4];
#pragma unroll
  for (int fi = 0; fi < 2; ++fi)
#pragma unroll
    for (int kt = 0; kt < 4; ++kt) {
      ah[fi][kt] = *reinterpret_cast<const bf16x8*>(Ah + fi * 16 * DD + kt * 32);
      al[fi][kt] = *reinterpret_cast<const bf16x8*>(Al + fi * 16 * DD + kt * 32);
    }

  float si[2][4]; int li[2][4];
#pragma unroll
  for (int fi = 0; fi < 2; ++fi)
#pragma unroll
    for (int r = 0; r < 4; ++r) {
      const int row = row0 + fi * 16 + lg * 4 + r;
      si[fi][r] = sq[row];
      li[fi][r] = labels[row];
    }

  f32x4 acc[2][8];
#pragma unroll
  for (int fi = 0; fi < 2; ++fi)
#pragma unroll
    for (int fj = 0; fj < 8; ++fj) acc[fi][fj] = (f32x4){0.f, 0.f, 0.f, 0.f};

#pragma unroll
  for (int fj = 0; fj < 8; ++fj) {
    bf16x8 bh[4], bl[4];
#pragma unroll
    for (int kt = 0; kt < 4; ++kt) {
      bh[kt] = *reinterpret_cast<const bf16x8*>(Bh + fj * 16 * DD + kt * 32);
      bl[kt] = *reinterpret_cast<const bf16x8*>(Bl + fj * 16 * DD + kt * 32);
    }
#pragma unroll
    for (int kt = 0; kt < 4; ++kt)
#pragma unroll
      for (int fi = 0; fi < 2; ++fi) {
        acc[fi][fj] = __builtin_amdgcn_mfma_f32_16x16x32_bf16(ah[fi][kt], bh[kt], acc[fi][fj], 0, 0, 0);
        acc[fi][fj] = __builtin_amdgcn_mfma_f32_16x16x32_bf16(ah[fi][kt], bl[kt], acc[fi][fj], 0, 0, 0);
        acc[fi][fj] = __builtin_amdgcn_mfma_f32_16x16x32_bf16(al[fi][kt], bh[kt], acc[fi][fj], 0, 0, 0);
      }
  }

  // epilogue: per-pair transform, accumulate row stats in registers
  float dacc[2][4] = {}, pacc[2][4] = {}, nacc[2][4] = {};
#pragma unroll
  for (int fj = 0; fj < 8; ++fj) {
    const int col = col0 + fj * 16 + ln;
    const float sjv = sq[col];
    const int   ljv = labels[col];
    const float qv = C_CONST * sjv;
    const float b  = 1.f - qv;
    const float b2 = b * b;
#pragma unroll
    for (int fi = 0; fi < 2; ++fi)
#pragma unroll
      for (int r = 0; r < 4; ++r) {
        const int row = row0 + fi * 16 + lg * 4 + r;
        const float g   = acc[fi][fj][r];
        const float pi_ = C_CONST * si[fi][r];
        const float tt  = fmaf(-2.f * C_CONST, g, 1.f);   // 1 - 2Cg
        const float a   = tt + pi_;                       // 1 - 2Cg + C si
        const float den = fabsf(fmaf(pi_, qv, tt));       // |1-2Cg+C^2 si sj|
        float ns = a * a * sjv;
        ns = fmaf(b2, si[fi][r], ns);
        ns = fmaf(-2.f * a * b, g, ns);
        ns = fmaxf(ns, 0.f);
        const float rr = __builtin_amdgcn_sqrtf(C_CONST * ns);
        float ratio = (den - rr) * __builtin_amdgcn_rcpf(den + rr);
        ratio = fmaxf(ratio, RATIO_MIN);
        const float P = __builtin_amdgcn_logf(ratio);     // log2(ratio)
        const float e = __builtin_amdgcn_exp2f(20.f * P); // exp(logit)
        const bool diag = (col == row);
        const bool same = (ljv == li[fi][r]) && !diag;
        dacc[fi][r] += diag ? 0.f : e;
        pacc[fi][r] += same ? LOGIT_SCALE * P : 0.f;
        nacc[fi][r] += same ? 1.f : 0.f;
      }
  }

  // reduce over the 16 ln lanes; plain partial stores (no atomics)
#pragma unroll
  for (int fi = 0; fi < 2; ++fi)
#pragma unroll
    for (int r = 0; r < 4; ++r) {
      float d = dacc[fi][r], p = pacc[fi][r], n = nacc[fi][r];
#pragma unroll
      for (int off = 1; off < 16; off <<= 1) {
        d += __shfl_xor(d, off);
        p += __shfl_xor(p, off);
        n += __shfl_xor(n, off);
      }
      if (ln == 0) {
        const size_t idx = (size_t)s * B + (row0 + fi * 16 + lg * 4 + r);
        dpart[idx] = d;
        ppart[idx] = p;
        npart[idx] = n;
      }
    }
}

// stage 1: one row per thread, 16 blocks; per-block scalar partials
__global__ __launch_bounds__(256) void finalize_part(
    const float* __restrict__ dpart, const float* __restrict__ ppart,
    const float* __restrict__ npart, float* __restrict__ lossP,
    float* __restrict__ validP, int B) {
  const int i = blockIdx.x * 256 + threadIdx.x;
  float d = 0.f, p = 0.f, n = 0.f;
#pragma unroll
  for (int s = 0; s < NSPLIT; ++s) {
    d += dpart[(size_t)s * B + i];     // coalesced across threads
    p += ppart[(size_t)s * B + i];
    n += npart[(size_t)s * B + i];
  }
  float s_loss = 0.f, s_valid = 0.f;
  if (n > 0.f) {
    float ln_d = __builtin_amdgcn_logf(d) * LN2;
    float rl = -(p - n * ln_d) / n * TEMP;
    if (!(rl != rl)) s_loss = rl;      // NaN -> 0 like reference
    s_valid = 1.f;
  }
#pragma unroll
  for (int off = 1; off < 64; off <<= 1) {
    s_loss += __shfl_xor(s_loss, off);
    s_valid += __shfl_xor(s_valid, off);
  }
  __shared__ float red[8];
  const int wid = threadIdx.x >> 6;
  if ((threadIdx.x & 63) == 0) { red[wid] = s_loss; red[wid + 4] = s_valid; }
  __syncthreads();
  if (threadIdx.x == 0) {
    lossP[blockIdx.x]  = red[0] + red[1] + red[2] + red[3];
    validP[blockIdx.x] = red[4] + red[5] + red[6] + red[7];
  }
}

// stage 2: tiny final reduce
__global__ void finalize_final(const float* __restrict__ lossP,
                               const float* __restrict__ validP,
                               float* __restrict__ out) {
  const int t = threadIdx.x;          // 64 lanes, first FBLK active
  float L = (t < FBLK) ? lossP[t] : 0.f;
  float V = (t < FBLK) ? validP[t] : 0.f;
#pragma unroll
  for (int off = 1; off < 64; off <<= 1) {
    L += __shfl_xor(L, off);
    V += __shfl_xor(V, off);
  }
  if (t == 0) out[0] = L / fmaxf(V, 1.f);
}

extern "C" void kernel_launch(void* const* d_in, const int* in_sizes, int n_in,
                              void* d_out, int out_size, void* d_ws, size_t ws_size,
                              hipStream_t stream) {
  const float* F = (const float*)d_in[0];
  const int* labels = (const int*)d_in[1];
  const int B = in_sizes[1];           // 4096

  float* sq    = (float*)d_ws;
  float* dpart = sq + B;
  float* ppart = dpart + (size_t)NSPLIT * B;
  float* npart = ppart + (size_t)NSPLIT * B;
  float* lossP = npart + (size_t)NSPLIT * B;
  float* validP = lossP + FBLK;
  __bf16* Fh = (__bf16*)(validP + FBLK);
  __bf16* Fl = Fh + (size_t)B * DD;

  prep_kernel<<<dim3(B / 8), dim3(256), 0, stream>>>(F, Fh, Fl, sq);
  gram_kernel<<<dim3(B / 128, NSPLIT), dim3(256), 0, stream>>>(
      Fh, Fl, sq, labels, dpart, ppart, npart, B);
  finalize_part<<<dim3(FBLK), dim3(256), 0, stream>>>(
      dpart, ppart, npart, lossP, validP, B);
  finalize_final<<<1, dim3(64), 0, stream>>>(lossP, validP, (float*)d_out);
}

// Round 7
// 81.569 us; speedup vs baseline: 1.1628x; 1.1628x over previous
//
#include <hip/hip_runtime.h>
#include <cstddef>

// Hyperbolic supervised contrastive loss, fused, MFMA split-bf16 Gram.
// G = F F^T with F = hi + lo (bf16 split): G ~= hi*hi^T + hi*lo^T + lo*hi^T.
// logits_max cancels (softmax shift invariance).
// Row-stationary, one 128x128 tile per block, grid 32x32 = 1024 blocks = 4/CU.
// launch_bounds (256,2): round 6's (256,4) pin forced a 128-reg cap -> massive
// scratch spill (WRITE_SIZE 10->74 MB). 128 VGPR at (256,2) already allows
// 4 waves/SIMD in HW; the grid supplies the occupancy.
// Row stats -> per-split partial stores (no atomics), parallel finalize.
// exp(logit) = ratio^20, logit = 20*ln2*log2(ratio), ratio=(|den|-r)/(|den|+r).

typedef __bf16 bf16x8 __attribute__((ext_vector_type(8)));
typedef __bf16 bf16x4 __attribute__((ext_vector_type(4)));
typedef float  f32x4  __attribute__((ext_vector_type(4)));

#define C_CONST 0.01f
#define RATIO_MIN 5.000025e-06f           // ratio at clamp 1-1e-5
#define LOGIT_SCALE 13.86294361119890619f // 20*ln(2)
#define TEMP 0.5f
#define LN2 0.69314718055994530942f
constexpr int DD = 128;
constexpr int NSPLIT = 32;   // one 128-col tile per split
constexpr int FBLK = 16;     // finalize blocks

// bf16-split + row squared-norms. 8 rows/block, 32 lanes/row.
__global__ __launch_bounds__(256) void prep_kernel(
    const float* __restrict__ F, __bf16* __restrict__ Fh, __bf16* __restrict__ Fl,
    float* __restrict__ sq) {
  const int tid = threadIdx.x;
  const int lane = tid & 31;
  const int row = blockIdx.x * 8 + (tid >> 5);
  const float4 v = *reinterpret_cast<const float4*>(F + (size_t)row * DD + lane * 4);
  float s = v.x * v.x + v.y * v.y + v.z * v.z + v.w * v.w;
  bf16x4 h, lo;
  h[0] = (__bf16)v.x; lo[0] = (__bf16)(v.x - (float)h[0]);
  h[1] = (__bf16)v.y; lo[1] = (__bf16)(v.y - (float)h[1]);
  h[2] = (__bf16)v.z; lo[2] = (__bf16)(v.z - (float)h[2]);
  h[3] = (__bf16)v.w; lo[3] = (__bf16)(v.w - (float)h[3]);
  *reinterpret_cast<bf16x4*>(Fh + (size_t)row * DD + lane * 4) = h;
  *reinterpret_cast<bf16x4*>(Fl + (size_t)row * DD + lane * 4) = lo;
#pragma unroll
  for (int off = 1; off < 32; off <<= 1) s += __shfl_xor(s, off);
  if (lane == 0) sq[row] = s;
}

// 4 waves; wave w owns rows row0..row0+31 (2 row-frags x 8 col-frags).
// A frags hoisted to regs, B frags streamed from L2 per fj.
// C/D layout (verified m89): value r of frag (fi,fj) at
// row = row0 + fi*16 + lg*4 + r, col = col0 + fj*16 + ln.
__global__ __launch_bounds__(256, 2) void gram_kernel(
    const __bf16* __restrict__ Fh, const __bf16* __restrict__ Fl,
    const float* __restrict__ sq, const int* __restrict__ labels,
    float* __restrict__ dpart, float* __restrict__ ppart, float* __restrict__ npart,
    int B) {
  const int tid = threadIdx.x;
  const int l  = tid & 63;
  const int w  = tid >> 6;
  const int lg = l >> 4, ln = l & 15;
  const int row0 = blockIdx.x * 128 + w * 32;
  const int s = blockIdx.y;
  const int col0 = s * 128;

  const __bf16* Ah = Fh + (size_t)(row0 + ln) * DD + lg * 8;
  const __bf16* Al = Fl + (size_t)(row0 + ln) * DD + lg * 8;
  const __bf16* Bh = Fh + (size_t)(col0 + ln) * DD + lg * 8;
  const __bf16* Bl = Fl + (size_t)(col0 + ln) * DD + lg * 8;

  // hoist all A fragments (16 x 16B = 64 VGPR)
  bf16x8 ah[2][4], al[2][4];
#pragma unroll
  for (int fi = 0; fi < 2; ++fi)
#pragma unroll
    for (int kt = 0; kt < 4; ++kt) {
      ah[fi][kt] = *reinterpret_cast<const bf16x8*>(Ah + fi * 16 * DD + kt * 32);
      al[fi][kt] = *reinterpret_cast<const bf16x8*>(Al + fi * 16 * DD + kt * 32);
    }

  float si[2][4]; int li[2][4];
#pragma unroll
  for (int fi = 0; fi < 2; ++fi)
#pragma unroll
    for (int r = 0; r < 4; ++r) {
      const int row = row0 + fi * 16 + lg * 4 + r;
      si[fi][r] = sq[row];
      li[fi][r] = labels[row];
    }

  f32x4 acc[2][8];
#pragma unroll
  for (int fi = 0; fi < 2; ++fi)
#pragma unroll
    for (int fj = 0; fj < 8; ++fj) acc[fi][fj] = (f32x4){0.f, 0.f, 0.f, 0.f};

#pragma unroll
  for (int fj = 0; fj < 8; ++fj) {
    bf16x8 bh[4], bl[4];
#pragma unroll
    for (int kt = 0; kt < 4; ++kt) {
      bh[kt] = *reinterpret_cast<const bf16x8*>(Bh + fj * 16 * DD + kt * 32);
      bl[kt] = *reinterpret_cast<const bf16x8*>(Bl + fj * 16 * DD + kt * 32);
    }
#pragma unroll
    for (int kt = 0; kt < 4; ++kt)
#pragma unroll
      for (int fi = 0; fi < 2; ++fi) {
        acc[fi][fj] = __builtin_amdgcn_mfma_f32_16x16x32_bf16(ah[fi][kt], bh[kt], acc[fi][fj], 0, 0, 0);
        acc[fi][fj] = __builtin_amdgcn_mfma_f32_16x16x32_bf16(ah[fi][kt], bl[kt], acc[fi][fj], 0, 0, 0);
        acc[fi][fj] = __builtin_amdgcn_mfma_f32_16x16x32_bf16(al[fi][kt], bh[kt], acc[fi][fj], 0, 0, 0);
      }
  }

  // epilogue: per-pair transform, accumulate row stats in registers
  float dacc[2][4] = {}, pacc[2][4] = {}, nacc[2][4] = {};
#pragma unroll
  for (int fj = 0; fj < 8; ++fj) {
    const int col = col0 + fj * 16 + ln;
    const float sjv = sq[col];
    const int   ljv = labels[col];
    const float qv = C_CONST * sjv;
    const float b  = 1.f - qv;
    const float b2 = b * b;
#pragma unroll
    for (int fi = 0; fi < 2; ++fi)
#pragma unroll
      for (int r = 0; r < 4; ++r) {
        const int row = row0 + fi * 16 + lg * 4 + r;
        const float g   = acc[fi][fj][r];
        const float pi_ = C_CONST * si[fi][r];
        const float tt  = fmaf(-2.f * C_CONST, g, 1.f);   // 1 - 2Cg
        const float a   = tt + pi_;                       // 1 - 2Cg + C si
        const float den = fabsf(fmaf(pi_, qv, tt));       // |1-2Cg+C^2 si sj|
        float ns = a * a * sjv;
        ns = fmaf(b2, si[fi][r], ns);
        ns = fmaf(-2.f * a * b, g, ns);
        ns = fmaxf(ns, 0.f);
        const float rr = __builtin_amdgcn_sqrtf(C_CONST * ns);
        float ratio = (den - rr) * __builtin_amdgcn_rcpf(den + rr);
        ratio = fmaxf(ratio, RATIO_MIN);
        const float P = __builtin_amdgcn_logf(ratio);     // log2(ratio)
        const float e = __builtin_amdgcn_exp2f(20.f * P); // exp(logit)
        const bool diag = (col == row);
        const bool same = (ljv == li[fi][r]) && !diag;
        dacc[fi][r] += diag ? 0.f : e;
        pacc[fi][r] += same ? LOGIT_SCALE * P : 0.f;
        nacc[fi][r] += same ? 1.f : 0.f;
      }
  }

  // reduce over the 16 ln lanes; plain partial stores (no atomics)
#pragma unroll
  for (int fi = 0; fi < 2; ++fi)
#pragma unroll
    for (int r = 0; r < 4; ++r) {
      float d = dacc[fi][r], p = pacc[fi][r], n = nacc[fi][r];
#pragma unroll
      for (int off = 1; off < 16; off <<= 1) {
        d += __shfl_xor(d, off);
        p += __shfl_xor(p, off);
        n += __shfl_xor(n, off);
      }
      if (ln == 0) {
        const size_t idx = (size_t)s * B + (row0 + fi * 16 + lg * 4 + r);
        dpart[idx] = d;
        ppart[idx] = p;
        npart[idx] = n;
      }
    }
}

// stage 1: one row per thread, 16 blocks; per-block scalar partials
__global__ __launch_bounds__(256) void finalize_part(
    const float* __restrict__ dpart, const float* __restrict__ ppart,
    const float* __restrict__ npart, float* __restrict__ lossP,
    float* __restrict__ validP, int B) {
  const int i = blockIdx.x * 256 + threadIdx.x;
  float d = 0.f, p = 0.f, n = 0.f;
#pragma unroll
  for (int s = 0; s < NSPLIT; ++s) {
    d += dpart[(size_t)s * B + i];     // coalesced across threads
    p += ppart[(size_t)s * B + i];
    n += npart[(size_t)s * B + i];
  }
  float s_loss = 0.f, s_valid = 0.f;
  if (n > 0.f) {
    float ln_d = __builtin_amdgcn_logf(d) * LN2;
    float rl = -(p - n * ln_d) / n * TEMP;
    if (!(rl != rl)) s_loss = rl;      // NaN -> 0 like reference
    s_valid = 1.f;
  }
#pragma unroll
  for (int off = 1; off < 64; off <<= 1) {
    s_loss += __shfl_xor(s_loss, off);
    s_valid += __shfl_xor(s_valid, off);
  }
  __shared__ float red[8];
  const int wid = threadIdx.x >> 6;
  if ((threadIdx.x & 63) == 0) { red[wid] = s_loss; red[wid + 4] = s_valid; }
  __syncthreads();
  if (threadIdx.x == 0) {
    lossP[blockIdx.x]  = red[0] + red[1] + red[2] + red[3];
    validP[blockIdx.x] = red[4] + red[5] + red[6] + red[7];
  }
}

// stage 2: tiny final reduce
__global__ void finalize_final(const float* __restrict__ lossP,
                               const float* __restrict__ validP,
                               float* __restrict__ out) {
  const int t = threadIdx.x;          // 64 lanes, first FBLK active
  float L = (t < FBLK) ? lossP[t] : 0.f;
  float V = (t < FBLK) ? validP[t] : 0.f;
#pragma unroll
  for (int off = 1; off < 64; off <<= 1) {
    L += __shfl_xor(L, off);
    V += __shfl_xor(V, off);
  }
  if (t == 0) out[0] = L / fmaxf(V, 1.f);
}

extern "C" void kernel_launch(void* const* d_in, const int* in_sizes, int n_in,
                              void* d_out, int out_size, void* d_ws, size_t ws_size,
                              hipStream_t stream) {
  const float* F = (const float*)d_in[0];
  const int* labels = (const int*)d_in[1];
  const int B = in_sizes[1];           // 4096

  float* sq    = (float*)d_ws;
  float* dpart = sq + B;
  float* ppart = dpart + (size_t)NSPLIT * B;
  float* npart = ppart + (size_t)NSPLIT * B;
  float* lossP = npart + (size_t)NSPLIT * B;
  float* validP = lossP + FBLK;
  __bf16* Fh = (__bf16*)(validP + FBLK);
  __bf16* Fl = Fh + (size_t)B * DD;

  prep_kernel<<<dim3(B / 8), dim3(256), 0, stream>>>(F, Fh, Fl, sq);
  gram_kernel<<<dim3(B / 128, NSPLIT), dim3(256), 0, stream>>>(
      Fh, Fl, sq, labels, dpart, ppart, npart, B);
  finalize_part<<<dim3(FBLK), dim3(256), 0, stream>>>(
      dpart, ppart, npart, lossP, validP, B);
  finalize_final<<<1, dim3(64), 0, stream>>>(lossP, validP, (float*)d_out);
}

// Round 8
// 59.371 us; speedup vs baseline: 1.5976x; 1.3739x over previous
//
#include <hip/hip_runtime.h>
#include <cstddef>

// Hyperbolic supervised contrastive loss, fused, MFMA split-bf16 Gram.
// G = F F^T with F = hi + lo (bf16 split): G ~= hi*hi^T + hi*lo^T + lo*hi^T.
// logits_max cancels (softmax shift invariance).
// Block (bi,s): rows bi*128..+127 vs cols s*128..+127. B-tile (hi+lo, 64 KB)
// staged in LDS ONCE per block (rounds 3-7 were latency-bound: every wave
// re-loaded the whole B tile from L2, 8-dependent-load chains, 65% stall).
// LDS layout: 16B chunks XOR-swizzled within each row (c ^= row&7) ->
// conflict-free ds_read_b128; staged with linear dest + pre-swizzled source.
// Per fj: 8 ds_read + 24 MFMA + immediate epilogue (acc = 8 regs; fj+1 loads
// overlap fj epilogue VALU). exp(logit) = ratio^20 via 5 mults (trans 4->3).
// Row stats -> per-split partial stores (no atomics), parallel finalize.

typedef __bf16 bf16x8 __attribute__((ext_vector_type(8)));
typedef __bf16 bf16x4 __attribute__((ext_vector_type(4)));
typedef float  f32x4  __attribute__((ext_vector_type(4)));

#define C_CONST 0.01f
#define RATIO_MIN 5.000025e-06f           // ratio at clamp 1-1e-5
#define LOGIT_SCALE 13.86294361119890619f // 20*ln(2)
#define TEMP 0.5f
#define LN2 0.69314718055994530942f
constexpr int DD = 128;
constexpr int NSPLIT = 32;   // one 128-col tile per split
constexpr int FBLK = 16;     // finalize blocks

// bf16-split + row squared-norms. 8 rows/block, 32 lanes/row.
__global__ __launch_bounds__(256) void prep_kernel(
    const float* __restrict__ F, __bf16* __restrict__ Fh, __bf16* __restrict__ Fl,
    float* __restrict__ sq) {
  const int tid = threadIdx.x;
  const int lane = tid & 31;
  const int row = blockIdx.x * 8 + (tid >> 5);
  const float4 v = *reinterpret_cast<const float4*>(F + (size_t)row * DD + lane * 4);
  float s = v.x * v.x + v.y * v.y + v.z * v.z + v.w * v.w;
  bf16x4 h, lo;
  h[0] = (__bf16)v.x; lo[0] = (__bf16)(v.x - (float)h[0]);
  h[1] = (__bf16)v.y; lo[1] = (__bf16)(v.y - (float)h[1]);
  h[2] = (__bf16)v.z; lo[2] = (__bf16)(v.z - (float)h[2]);
  h[3] = (__bf16)v.w; lo[3] = (__bf16)(v.w - (float)h[3]);
  *reinterpret_cast<bf16x4*>(Fh + (size_t)row * DD + lane * 4) = h;
  *reinterpret_cast<bf16x4*>(Fl + (size_t)row * DD + lane * 4) = lo;
#pragma unroll
  for (int off = 1; off < 32; off <<= 1) s += __shfl_xor(s, off);
  if (lane == 0) sq[row] = s;
}

// 4 waves; wave w owns rows row0..row0+31 (2 row-frags).
// C/D layout (verified m89): value r of frag (fi,fj) at
// row = row0 + fi*16 + lg*4 + r, col = col0 + fj*16 + ln.
__global__ __launch_bounds__(256, 2) void gram_kernel(
    const __bf16* __restrict__ Fh, const __bf16* __restrict__ Fl,
    const float* __restrict__ sq, const int* __restrict__ labels,
    float* __restrict__ dpart, float* __restrict__ ppart, float* __restrict__ npart,
    int B) {
  __shared__ __bf16 Bs[2 * 128 * 128];   // 64 KB: [hi | lo], chunk-XOR swizzle
  char* BsB = reinterpret_cast<char*>(Bs);

  const int tid = threadIdx.x;
  const int l  = tid & 63;
  const int w  = tid >> 6;
  const int lg = l >> 4, ln = l & 15;
  const int lx = ln & 7;
  const int row0 = blockIdx.x * 128 + w * 32;
  const int col0 = blockIdx.y * 128;

  // --- stage B tile hi+lo into LDS: linear dest, source chunk pre-swizzled
  // LDS chunk k (16B) of row r holds global chunk ( (k&15) ^ (r&7) ) of row r.
#pragma unroll
  for (int j = 0; j < 8; ++j) {
    const int k = tid + j * 256;            // chunk id 0..2047 (hi)
    const int row = k >> 4;
    const int cc = (k & 15) ^ (row & 7);
    bf16x8 v = *reinterpret_cast<const bf16x8*>(Fh + (size_t)(col0 + row) * DD + cc * 8);
    *reinterpret_cast<bf16x8*>(BsB + (size_t)k * 16) = v;
  }
#pragma unroll
  for (int j = 0; j < 8; ++j) {
    const int k = tid + j * 256;            // chunk id 0..2047 (lo)
    const int row = k >> 4;
    const int cc = (k & 15) ^ (row & 7);
    bf16x8 v = *reinterpret_cast<const bf16x8*>(Fl + (size_t)(col0 + row) * DD + cc * 8);
    *reinterpret_cast<bf16x8*>(BsB + 32768 + (size_t)k * 16) = v;
  }

  // --- A fragments to regs (independent of LDS staging; overlaps)
  const __bf16* Ahp = Fh + (size_t)(row0 + ln) * DD + lg * 8;
  const __bf16* Alp = Fl + (size_t)(row0 + ln) * DD + lg * 8;
  bf16x8 ah[2][4], alr[2][4];
#pragma unroll
  for (int fi = 0; fi < 2; ++fi)
#pragma unroll
    for (int kt = 0; kt < 4; ++kt) {
      ah[fi][kt]  = *reinterpret_cast<const bf16x8*>(Ahp + fi * 16 * DD + kt * 32);
      alr[fi][kt] = *reinterpret_cast<const bf16x8*>(Alp + fi * 16 * DD + kt * 32);
    }

  float si[2][4]; int li[2][4];
#pragma unroll
  for (int fi = 0; fi < 2; ++fi)
#pragma unroll
    for (int r = 0; r < 4; ++r) {
      const int row = row0 + fi * 16 + lg * 4 + r;
      si[fi][r] = sq[row];
      li[fi][r] = labels[row];
    }

  __syncthreads();

  float dacc[2][4] = {}, pacc[2][4] = {}, nacc[2][4] = {};

#pragma unroll
  for (int fj = 0; fj < 8; ++fj) {
    // 8 conflict-free ds_read_b128 (bank group = ((kt*4+lg)^lx)&7, 8-way tiled)
    const int rbase = (fj * 16 + ln) * 256;
    bf16x8 bh[4], bl[4];
#pragma unroll
    for (int kt = 0; kt < 4; ++kt) {
      const int off = rbase + ((((kt * 4 + lg) ^ lx)) << 4);
      bh[kt] = *reinterpret_cast<const bf16x8*>(BsB + off);
      bl[kt] = *reinterpret_cast<const bf16x8*>(BsB + 32768 + off);
    }

    f32x4 a0 = (f32x4){0.f, 0.f, 0.f, 0.f};
    f32x4 a1 = (f32x4){0.f, 0.f, 0.f, 0.f};
#pragma unroll
    for (int kt = 0; kt < 4; ++kt) {
      a0 = __builtin_amdgcn_mfma_f32_16x16x32_bf16(ah[0][kt],  bh[kt], a0, 0, 0, 0);
      a0 = __builtin_amdgcn_mfma_f32_16x16x32_bf16(alr[0][kt], bh[kt], a0, 0, 0, 0);
      a0 = __builtin_amdgcn_mfma_f32_16x16x32_bf16(ah[0][kt],  bl[kt], a0, 0, 0, 0);
      a1 = __builtin_amdgcn_mfma_f32_16x16x32_bf16(ah[1][kt],  bh[kt], a1, 0, 0, 0);
      a1 = __builtin_amdgcn_mfma_f32_16x16x32_bf16(alr[1][kt], bh[kt], a1, 0, 0, 0);
      a1 = __builtin_amdgcn_mfma_f32_16x16x32_bf16(ah[1][kt],  bl[kt], a1, 0, 0, 0);
    }

    // fused epilogue for these 16 cols (overlaps next fj's ds_reads/MFMAs)
    const int col = col0 + fj * 16 + ln;
    const float sjv = sq[col];
    const int   ljv = labels[col];
    const float qv = C_CONST * sjv;
    const float b  = 1.f - qv;
    const float b2 = b * b;
#pragma unroll
    for (int fi = 0; fi < 2; ++fi) {
      const f32x4 av = fi ? a1 : a0;
#pragma unroll
      for (int r = 0; r < 4; ++r) {
        const int row = row0 + fi * 16 + lg * 4 + r;
        const float g   = av[r];
        const float pi_ = C_CONST * si[fi][r];
        const float tt  = fmaf(-2.f * C_CONST, g, 1.f);   // 1 - 2Cg
        const float a   = tt + pi_;                       // 1 - 2Cg + C si
        const float den = fabsf(fmaf(pi_, qv, tt));       // |1-2Cg+C^2 si sj|
        float ns = a * a * sjv;
        ns = fmaf(b2, si[fi][r], ns);
        ns = fmaf(-2.f * a * b, g, ns);
        ns = fmaxf(ns, 0.f);
        const float rr = __builtin_amdgcn_sqrtf(C_CONST * ns);
        float ratio = (den - rr) * __builtin_amdgcn_rcpf(den + rr);
        ratio = fmaxf(ratio, RATIO_MIN);
        const float P = __builtin_amdgcn_logf(ratio);     // log2(ratio)
        const float t2 = ratio * ratio;                   // e = ratio^20, full-rate
        const float t4 = t2 * t2;
        const float t5 = t4 * ratio;
        const float t10 = t5 * t5;
        const float e = t10 * t10;
        const bool diag = (col == row);
        const bool same = (ljv == li[fi][r]) && !diag;
        dacc[fi][r] += diag ? 0.f : e;
        pacc[fi][r] += same ? LOGIT_SCALE * P : 0.f;
        nacc[fi][r] += same ? 1.f : 0.f;
      }
    }
  }

  // reduce over the 16 ln lanes; plain partial stores (no atomics)
#pragma unroll
  for (int fi = 0; fi < 2; ++fi)
#pragma unroll
    for (int r = 0; r < 4; ++r) {
      float d = dacc[fi][r], p = pacc[fi][r], n = nacc[fi][r];
#pragma unroll
      for (int off = 1; off < 16; off <<= 1) {
        d += __shfl_xor(d, off);
        p += __shfl_xor(p, off);
        n += __shfl_xor(n, off);
      }
      if (ln == 0) {
        const size_t idx = (size_t)blockIdx.y * B + (row0 + fi * 16 + lg * 4 + r);
        dpart[idx] = d;
        ppart[idx] = p;
        npart[idx] = n;
      }
    }
}

// stage 1: one row per thread, 16 blocks; per-block scalar partials
__global__ __launch_bounds__(256) void finalize_part(
    const float* __restrict__ dpart, const float* __restrict__ ppart,
    const float* __restrict__ npart, float* __restrict__ lossP,
    float* __restrict__ validP, int B) {
  const int i = blockIdx.x * 256 + threadIdx.x;
  float d = 0.f, p = 0.f, n = 0.f;
#pragma unroll
  for (int s = 0; s < NSPLIT; ++s) {
    d += dpart[(size_t)s * B + i];     // coalesced across threads
    p += ppart[(size_t)s * B + i];
    n += npart[(size_t)s * B + i];
  }
  float s_loss = 0.f, s_valid = 0.f;
  if (n > 0.f) {
    float ln_d = __builtin_amdgcn_logf(d) * LN2;
    float rl = -(p - n * ln_d) / n * TEMP;
    if (!(rl != rl)) s_loss = rl;      // NaN -> 0 like reference
    s_valid = 1.f;
  }
#pragma unroll
  for (int off = 1; off < 64; off <<= 1) {
    s_loss += __shfl_xor(s_loss, off);
    s_valid += __shfl_xor(s_valid, off);
  }
  __shared__ float red[8];
  const int wid = threadIdx.x >> 6;
  if ((threadIdx.x & 63) == 0) { red[wid] = s_loss; red[wid + 4] = s_valid; }
  __syncthreads();
  if (threadIdx.x == 0) {
    lossP[blockIdx.x]  = red[0] + red[1] + red[2] + red[3];
    validP[blockIdx.x] = red[4] + red[5] + red[6] + red[7];
  }
}

// stage 2: tiny final reduce
__global__ void finalize_final(const float* __restrict__ lossP,
                               const float* __restrict__ validP,
                               float* __restrict__ out) {
  const int t = threadIdx.x;          // 64 lanes, first FBLK active
  float L = (t < FBLK) ? lossP[t] : 0.f;
  float V = (t < FBLK) ? validP[t] : 0.f;
#pragma unroll
  for (int off = 1; off < 64; off <<= 1) {
    L += __shfl_xor(L, off);
    V += __shfl_xor(V, off);
  }
  if (t == 0) out[0] = L / fmaxf(V, 1.f);
}

extern "C" void kernel_launch(void* const* d_in, const int* in_sizes, int n_in,
                              void* d_out, int out_size, void* d_ws, size_t ws_size,
                              hipStream_t stream) {
  const float* F = (const float*)d_in[0];
  const int* labels = (const int*)d_in[1];
  const int B = in_sizes[1];           // 4096

  float* sq    = (float*)d_ws;
  float* dpart = sq + B;
  float* ppart = dpart + (size_t)NSPLIT * B;
  float* npart = ppart + (size_t)NSPLIT * B;
  float* lossP = npart + (size_t)NSPLIT * B;
  float* validP = lossP + FBLK;
  __bf16* Fh = (__bf16*)(validP + FBLK);
  __bf16* Fl = Fh + (size_t)B * DD;

  prep_kernel<<<dim3(B / 8), dim3(256), 0, stream>>>(F, Fh, Fl, sq);
  gram_kernel<<<dim3(B / 128, NSPLIT), dim3(256), 0, stream>>>(
      Fh, Fl, sq, labels, dpart, ppart, npart, B);
  finalize_part<<<dim3(FBLK), dim3(256), 0, stream>>>(
      dpart, ppart, npart, lossP, validP, B);
  finalize_final<<<1, dim3(64), 0, stream>>>(lossP, validP, (float*)d_out);
}